// Round 2
// baseline (656.768 us; speedup 1.0000x reference)
//
#include <hip/hip_runtime.h>
#include <math.h>

// GMM EM, M=4 mixtures x G=4 gaussians, C=3, EM_ITERS=3, EPS=1e-4.
// Pipeline: stats0 -> params -> em -> params -> em -> params -> final.
//
// R2: LDS segmented stats now use unsafeAtomicAdd (ds_add_f32, no CAS loop —
// atomicAdd(float) on LDS compiles to a ~200-cyc CAS loop, R1's 215us k_em).
// Accumulator layout: cluster t=m*4+g at slot t*16 (strides 64/16, both =0
// mod 32) with copy stride 257 (=1 mod 32) -> bank = lane%32 + const,
// conflict-free for any label mix.

#define NTHR  256
#define NBLK  1024         // grid for the heavy kernels (4 blocks/CU)
#define NCOPY 32           // LDS accumulator copies (threadIdx & 31)
#define CSTR  257          // copy stride in floats (256 slots + 1 pad)
#define SLOTS 256          // 16 clusters * 16 (10 stats + 6 pad)
#define EPS_F 1e-4f
#define LOG2PI3 5.5136311992280366f   // 3*ln(2*pi)

static __device__ __forceinline__ void stat_add(float* q, float w,
                                                float a, float b, float c) {
    float wa = w * a, wb = w * b, wc = w * c;
    unsafeAtomicAdd(q + 0, w);
    unsafeAtomicAdd(q + 1, wa);
    unsafeAtomicAdd(q + 2, wb);
    unsafeAtomicAdd(q + 3, wc);
    unsafeAtomicAdd(q + 4, wa * a);
    unsafeAtomicAdd(q + 5, wa * b);
    unsafeAtomicAdd(q + 6, wa * c);
    unsafeAtomicAdd(q + 7, wb * b);
    unsafeAtomicAdd(q + 8, wb * c);
    unsafeAtomicAdd(q + 9, wc * c);
}

// ---------- pass 1: initial resp = (m = label, g = n % 4) ----------
__global__ __launch_bounds__(NTHR) void k_stats0(const float* __restrict__ x,
                                                 const int* __restrict__ lab,
                                                 float* __restrict__ partials,
                                                 int N) {
    __shared__ __align__(16) float sacc[NCOPY * CSTR];
    for (int i = threadIdx.x; i < NCOPY * CSTR; i += NTHR) sacc[i] = 0.f;
    __syncthreads();
    float* my = &sacc[(threadIdx.x & (NCOPY - 1)) * CSTR];

    const int groups = N >> 2;
    const float4* x0p = (const float4*)x;
    const float4* x1p = (const float4*)(x + N);
    const float4* x2p = (const float4*)(x + 2 * N);
    const int4*   lp  = (const int4*)lab;
    const int stride = gridDim.x * NTHR;
    for (int i = blockIdx.x * NTHR + threadIdx.x; i < groups; i += stride) {
        float4 a = x0p[i], b = x1p[i], c = x2p[i];
        int4 m4 = lp[i];
        // pixel n = 4*i + j  ->  g = n % 4 = j; cluster slot = m*64 + g*16
        stat_add(my + (m4.x * 64 +  0), 1.0f, a.x, b.x, c.x);
        stat_add(my + (m4.y * 64 + 16), 1.0f, a.y, b.y, c.y);
        stat_add(my + (m4.z * 64 + 32), 1.0f, a.z, b.z, c.z);
        stat_add(my + (m4.w * 64 + 48), 1.0f, a.w, b.w, c.w);
    }
    __syncthreads();
    if (threadIdx.x < SLOTS) {
        float s = 0.f;
        #pragma unroll
        for (int cp = 0; cp < NCOPY; ++cp) s += sacc[cp * CSTR + threadIdx.x];
        partials[(size_t)threadIdx.x * gridDim.x + blockIdx.x] = s;
    }
}

// ---------- params: reduce partials, 16x 3x3 invert, emit E-step coeffs ----------
// partials slot layout: cluster t=(m*4+g) stats k at slot t*16 + k.
// params layout per cluster t, stride 12:
// [0..2]=P*mu, [3]=c0, [4..6]=-0.5*Pii, [7..9]=-Pij (01,02,12), [10..11]=pad
__global__ __launch_bounds__(1024) void k_params(const float* __restrict__ partials,
                                                 float* __restrict__ params,
                                                 int nb) {
    __shared__ float qs[4][SLOTS];
    __shared__ float sums[SLOTS];
    __shared__ float wtab[16];
    const int t = threadIdx.x & 255;
    const int q = threadIdx.x >> 8;          // 4 quarters over the block dim
    {
        const int per = nb >> 2;             // blocks per quarter
        const float4* p = (const float4*)(partials + (size_t)t * nb + q * per);
        float s = 0.f;
        #pragma unroll 8
        for (int i = 0; i < (per >> 2); ++i) {
            float4 v = p[i];
            s += (v.x + v.y) + (v.z + v.w);
        }
        qs[q][t] = s;
    }
    __syncthreads();
    if (threadIdx.x < SLOTS)
        sums[threadIdx.x] = qs[0][threadIdx.x] + qs[1][threadIdx.x]
                          + qs[2][threadIdx.x] + qs[3][threadIdx.x];
    __syncthreads();
    if (threadIdx.x < 16) wtab[threadIdx.x] = sums[threadIdx.x * 16] + EPS_F;
    __syncthreads();
    if (threadIdx.x < 16) {
        const int tt = threadIdx.x;
        const float* S = &sums[tt * 16];
        const float w  = wtab[tt];
        const float iw = 1.0f / w;
        float mu0 = S[1] * iw, mu1 = S[2] * iw, mu2 = S[3] * iw;
        float c00 = S[4] * iw - mu0 * mu0 + EPS_F;
        float c01 = S[5] * iw - mu0 * mu1;
        float c02 = S[6] * iw - mu0 * mu2;
        float c11 = S[7] * iw - mu1 * mu1 + EPS_F;
        float c12 = S[8] * iw - mu1 * mu2;
        float c22 = S[9] * iw - mu2 * mu2 + EPS_F;
        float d00 = c11 * c22 - c12 * c12;
        float d01 = c02 * c12 - c01 * c22;
        float d02 = c01 * c12 - c02 * c11;
        float det = c00 * d00 + c01 * d01 + c02 * d02;
        float idet = 1.0f / det;
        float P00 = d00 * idet, P01 = d01 * idet, P02 = d02 * idet;
        float P11 = (c00 * c22 - c02 * c02) * idet;
        float P12 = (c01 * c02 - c00 * c12) * idet;
        float P22 = (c00 * c11 - c01 * c01) * idet;
        float logdet = logf(det);
        const int mb = tt & 12;              // m*4
        float wsum = wtab[mb] + wtab[mb + 1] + wtab[mb + 2] + wtab[mb + 3];
        float logpi = logf(w) - logf(wsum);
        float pm0 = P00 * mu0 + P01 * mu1 + P02 * mu2;
        float pm1 = P01 * mu0 + P11 * mu1 + P12 * mu2;
        float pm2 = P02 * mu0 + P12 * mu1 + P22 * mu2;
        float mPm = mu0 * pm0 + mu1 * pm1 + mu2 * pm2;
        float c0 = logpi - 0.5f * (mPm + logdet + LOG2PI3);
        float* P = params + tt * 12;
        P[0] = pm0; P[1] = pm1; P[2] = pm2; P[3] = c0;
        P[4] = -0.5f * P00; P[5] = -0.5f * P11; P[6] = -0.5f * P22;
        P[7] = -P01; P[8] = -P02; P[9] = -P12;
        P[10] = 0.f; P[11] = 0.f;
    }
}

// ---------- fused E-step (own mixture only) + M-step stats ----------
static __device__ __forceinline__ void em_pixel(const float* __restrict__ spar,
                                                float* my,
                                                float a, float b, float c, int m) {
    const float* P0 = spar + m * 48;
    float xx00 = a * a, xx01 = a * b, xx02 = a * c;
    float xx11 = b * b, xx12 = b * c, xx22 = c * c;
    float l[4];
    #pragma unroll
    for (int g = 0; g < 4; ++g) {
        const float* P = P0 + g * 12;
        float4 q0 = *(const float4*)(P);
        float4 q1 = *(const float4*)(P + 4);
        float2 q2 = *(const float2*)(P + 8);
        l[g] = q0.w + q0.x * a + q0.y * b + q0.z * c
             + q1.x * xx00 + q1.y * xx11 + q1.z * xx22
             + q1.w * xx01 + q2.x * xx02 + q2.y * xx12;
    }
    float mx = fmaxf(fmaxf(l[0], l[1]), fmaxf(l[2], l[3]));
    float e0 = __expf(l[0] - mx), e1 = __expf(l[1] - mx);
    float e2 = __expf(l[2] - mx), e3 = __expf(l[3] - mx);
    float rs = 1.0f / (e0 + e1 + e2 + e3);
    float* q = my + m * 64;                  // cluster slot = m*64 + g*16
    stat_add(q +  0, e0 * rs, a, b, c);
    stat_add(q + 16, e1 * rs, a, b, c);
    stat_add(q + 32, e2 * rs, a, b, c);
    stat_add(q + 48, e3 * rs, a, b, c);
}

__global__ __launch_bounds__(NTHR) void k_em(const float* __restrict__ x,
                                             const int* __restrict__ lab,
                                             const float* __restrict__ params,
                                             float* __restrict__ partials,
                                             int N) {
    __shared__ __align__(16) float sacc[NCOPY * CSTR];
    __shared__ __align__(16) float spar[192];
    for (int i = threadIdx.x; i < NCOPY * CSTR; i += NTHR) sacc[i] = 0.f;
    if (threadIdx.x < 192) spar[threadIdx.x] = params[threadIdx.x];
    __syncthreads();
    float* my = &sacc[(threadIdx.x & (NCOPY - 1)) * CSTR];

    const int groups = N >> 2;
    const float4* x0p = (const float4*)x;
    const float4* x1p = (const float4*)(x + N);
    const float4* x2p = (const float4*)(x + 2 * N);
    const int4*   lp  = (const int4*)lab;
    const int stride = gridDim.x * NTHR;
    for (int i = blockIdx.x * NTHR + threadIdx.x; i < groups; i += stride) {
        float4 a = x0p[i], b = x1p[i], c = x2p[i];
        int4 m4 = lp[i];
        em_pixel(spar, my, a.x, b.x, c.x, m4.x);
        em_pixel(spar, my, a.y, b.y, c.y, m4.y);
        em_pixel(spar, my, a.z, b.z, c.z, m4.z);
        em_pixel(spar, my, a.w, b.w, c.w, m4.w);
    }
    __syncthreads();
    if (threadIdx.x < SLOTS) {
        float s = 0.f;
        #pragma unroll
        for (int cp = 0; cp < NCOPY; ++cp) s += sacc[cp * CSTR + threadIdx.x];
        partials[(size_t)threadIdx.x * gridDim.x + blockIdx.x] = s;
    }
}

// ---------- final: logp for all 16 gaussians -> logsumexp_g -> softmax_m ----------
static __device__ __forceinline__ void final_pixel(const float* __restrict__ PR,
                                                   float a, float b, float c,
                                                   float* post) {
    float xx00 = a * a, xx01 = a * b, xx02 = a * c;
    float xx11 = b * b, xx12 = b * c, xx22 = c * c;
    float ml[4];
    #pragma unroll
    for (int m = 0; m < 4; ++m) {
        float l[4];
        #pragma unroll
        for (int g = 0; g < 4; ++g) {
            const float* P = PR + (m * 4 + g) * 10;
            l[g] = P[3] + P[0] * a + P[1] * b + P[2] * c
                 + P[4] * xx00 + P[5] * xx11 + P[6] * xx22
                 + P[7] * xx01 + P[8] * xx02 + P[9] * xx12;
        }
        float mx = fmaxf(fmaxf(l[0], l[1]), fmaxf(l[2], l[3]));
        ml[m] = mx + __logf(__expf(l[0] - mx) + __expf(l[1] - mx)
                          + __expf(l[2] - mx) + __expf(l[3] - mx));
    }
    float mmx = fmaxf(fmaxf(ml[0], ml[1]), fmaxf(ml[2], ml[3]));
    float e0 = __expf(ml[0] - mmx), e1 = __expf(ml[1] - mmx);
    float e2 = __expf(ml[2] - mmx), e3 = __expf(ml[3] - mmx);
    float rs = 1.0f / (e0 + e1 + e2 + e3);
    post[0] = e0 * rs; post[1] = e1 * rs; post[2] = e2 * rs; post[3] = e3 * rs;
}

__global__ __launch_bounds__(NTHR) void k_final(const float* __restrict__ x,
                                                const float* __restrict__ params,
                                                float* __restrict__ out,
                                                int N) {
    __shared__ __align__(16) float spar[192];
    if (threadIdx.x < 192) spar[threadIdx.x] = params[threadIdx.x];
    __syncthreads();
    // hoist params into registers (static indexing only after full unroll)
    float PR[160];
    #pragma unroll
    for (int t = 0; t < 16; ++t) {
        #pragma unroll
        for (int k = 0; k < 10; ++k) PR[t * 10 + k] = spar[t * 12 + k];
    }
    const int groups = N >> 2;
    const float4* x0p = (const float4*)x;
    const float4* x1p = (const float4*)(x + N);
    const float4* x2p = (const float4*)(x + 2 * N);
    const int stride = gridDim.x * NTHR;
    for (int i = blockIdx.x * NTHR + threadIdx.x; i < groups; i += stride) {
        float4 a = x0p[i], b = x1p[i], c = x2p[i];
        float p0[4], p1[4], p2[4], p3[4];
        final_pixel(PR, a.x, b.x, c.x, p0);
        final_pixel(PR, a.y, b.y, c.y, p1);
        final_pixel(PR, a.z, b.z, c.z, p2);
        final_pixel(PR, a.w, b.w, c.w, p3);
        #pragma unroll
        for (int m = 0; m < 4; ++m) {
            ((float4*)(out + (size_t)m * N))[i] =
                make_float4(p0[m], p1[m], p2[m], p3[m]);
        }
    }
}

extern "C" void kernel_launch(void* const* d_in, const int* in_sizes, int n_in,
                              void* d_out, int out_size, void* d_ws, size_t ws_size,
                              hipStream_t stream) {
    const float* x   = (const float*)d_in[0];   // [3, N] float32
    const int*   lab = (const int*)d_in[1];     // [N] int32 in [0,4)
    float* out = (float*)d_out;                 // [4, N] float32
    const int N = in_sizes[1];

    int nb = NBLK;
    while (nb > 128 && ws_size < (size_t)(SLOTS * nb + 192) * sizeof(float)) nb >>= 1;
    float* partials = (float*)d_ws;             // [256][nb]
    float* params   = partials + (size_t)SLOTS * nb;  // [16*12]

    dim3 grid(nb), blk(NTHR);
    k_stats0<<<grid, blk, 0, stream>>>(x, lab, partials, N);
    k_params<<<dim3(1), dim3(1024), 0, stream>>>(partials, params, nb);
    k_em<<<grid, blk, 0, stream>>>(x, lab, params, partials, N);
    k_params<<<dim3(1), dim3(1024), 0, stream>>>(partials, params, nb);
    k_em<<<grid, blk, 0, stream>>>(x, lab, params, partials, N);
    k_params<<<dim3(1), dim3(1024), 0, stream>>>(partials, params, nb);
    k_final<<<grid, blk, 0, stream>>>(x, params, out, N);
}

// Round 3
// 214.279 us; speedup vs baseline: 3.0650x; 3.0650x over previous
//
#include <hip/hip_runtime.h>
#include <math.h>

// GMM EM, M=4 mixtures x G=4 gaussians, C=3, EM_ITERS=3, EPS=1e-4.
// Pipeline: accum(init) -> params -> accum(em) -> params -> accum(em) -> params -> final.
//
// R3: NO ATOMICS. R1/R2 proved LDS atomicAdd/unsafeAtomicAdd both compile to a
// ~CAS loop (identical 215us + identical conflict count). Replaced with a
// wave-synchronous transpose: lanes stage [w0..w3,a,b,c,label] (8 floats) in a
// wave-private LDS slab, then lane (t=cluster,p=phase) register-accumulates its
// cluster's 10 stats over 16 staged pixels (cndmask + 9 FMA each). Staged
// read banks {8p+g} / {8p+4..7}: conflict-free. No barriers in the hot loop
// (same-wave DS ops are processed in order).

#define NTHR  256
#define NBLK  1024
#define EPS_F 1e-4f
#define LOG2PI3 5.5136311992280366f   // 3*ln(2*pi)

// ---------- fused stats kernel: mode 0 = init (g = n%4), mode 1 = E+M step ----
__global__ __launch_bounds__(NTHR) void k_accum(const float* __restrict__ x,
                                                const int* __restrict__ lab,
                                                const float* __restrict__ params,
                                                float* __restrict__ partials,
                                                int N, int mode) {
    __shared__ __align__(16) float stage[NTHR / 64][64][8];  // wave-private slabs
    __shared__ __align__(16) float spar[192];
    __shared__ float red[NTHR / 64][160];
    const int tid  = threadIdx.x;
    const int wave = tid >> 6, lane = tid & 63;
    const int t  = lane >> 2, p = lane & 3;   // cluster t = m*4+g, pixel phase p
    const int tm = t >> 2,  tg = t & 3;
    if (mode && tid < 192) spar[tid] = params[tid];
    __syncthreads();

    float acc[10];
    #pragma unroll
    for (int k = 0; k < 10; ++k) acc[k] = 0.f;

    const int groups = N >> 2;
    const int stride = gridDim.x * NTHR;
    const int gid    = blockIdx.x * NTHR + tid;
    const int trips  = (groups + stride - 1) / stride;
    const float4* x0p = (const float4*)x;
    const float4* x1p = (const float4*)(x + N);
    const float4* x2p = (const float4*)(x + 2 * N);
    const int4*   lp  = (const int4*)lab;

    for (int tr = 0; tr < trips; ++tr) {
        const int i  = tr * stride + gid;
        const bool valid = i < groups;
        const int ii = valid ? i : (groups - 1);
        float4 va = x0p[ii], vb = x1p[ii], vc = x2p[ii];
        int4   m4 = lp[ii];
        float pa[4] = {va.x, va.y, va.z, va.w};
        float pb[4] = {vb.x, vb.y, vb.z, vb.w};
        float pc[4] = {vc.x, vc.y, vc.z, vc.w};
        int   pm[4] = {m4.x, m4.y, m4.z, m4.w};
        if (!valid) { pm[0] = pm[1] = pm[2] = pm[3] = -1; }

        #pragma unroll
        for (int j = 0; j < 4; ++j) {      // pixel n = 4*i + j  ->  n%4 = j
            const float a = pa[j], b = pb[j], c = pc[j];
            const int   m = pm[j];
            float w0, w1, w2, w3;
            if (mode) {
                const float* P0 = spar + (m & 3) * 48;
                float l[4];
                #pragma unroll
                for (int g = 0; g < 4; ++g) {
                    const float* P = P0 + g * 12;
                    float4 q0 = *(const float4*)(P);
                    float4 q1 = *(const float4*)(P + 4);
                    float2 q2 = *(const float2*)(P + 8);
                    l[g] = q0.w + q0.x * a + q0.y * b + q0.z * c
                         + q1.x * (a * a) + q1.y * (b * b) + q1.z * (c * c)
                         + q1.w * (a * b) + q2.x * (a * c) + q2.y * (b * c);
                }
                float mx = fmaxf(fmaxf(l[0], l[1]), fmaxf(l[2], l[3]));
                float e0 = __expf(l[0] - mx), e1 = __expf(l[1] - mx);
                float e2 = __expf(l[2] - mx), e3 = __expf(l[3] - mx);
                float rs = 1.0f / (e0 + e1 + e2 + e3);
                w0 = e0 * rs; w1 = e1 * rs; w2 = e2 * rs; w3 = e3 * rs;
            } else {
                w0 = (j == 0) ? 1.f : 0.f; w1 = (j == 1) ? 1.f : 0.f;
                w2 = (j == 2) ? 1.f : 0.f; w3 = (j == 3) ? 1.f : 0.f;
            }
            float* sl = &stage[wave][lane][0];
            ((float4*)sl)[0] = make_float4(w0, w1, w2, w3);
            ((float4*)sl)[1] = make_float4(a, b, c, __int_as_float(m));
            __builtin_amdgcn_wave_barrier();   // keep write->read order (0 instr)
            #pragma unroll
            for (int it = 0; it < 16; ++it) {
                const float* sq = &stage[wave][p + 4 * it][0];
                float  wv = sq[tg];
                float4 r  = ((const float4*)sq)[1];
                float sel = (__float_as_int(r.w) == tm) ? wv : 0.f;
                float sa = sel * r.x, sb = sel * r.y, sc = sel * r.z;
                acc[0] += sel;
                acc[1] = fmaf(sel, r.x, acc[1]);
                acc[2] = fmaf(sel, r.y, acc[2]);
                acc[3] = fmaf(sel, r.z, acc[3]);
                acc[4] = fmaf(sa, r.x, acc[4]);
                acc[5] = fmaf(sa, r.y, acc[5]);
                acc[6] = fmaf(sa, r.z, acc[6]);
                acc[7] = fmaf(sb, r.y, acc[7]);
                acc[8] = fmaf(sb, r.z, acc[8]);
                acc[9] = fmaf(sc, r.z, acc[9]);
            }
            __builtin_amdgcn_wave_barrier();   // keep read->next-write order
        }
    }

    // reduce over p (4 lanes per cluster) then across waves
    #pragma unroll
    for (int k = 0; k < 10; ++k) {
        acc[k] += __shfl_xor(acc[k], 1, 64);
        acc[k] += __shfl_xor(acc[k], 2, 64);
    }
    if (p == 0) {
        #pragma unroll
        for (int k = 0; k < 10; ++k) red[wave][t * 10 + k] = acc[k];
    }
    __syncthreads();
    if (tid < 160) {
        float s = red[0][tid] + red[1][tid] + red[2][tid] + red[3][tid];
        partials[(size_t)tid * gridDim.x + blockIdx.x] = s;
    }
}

// ---------- params: reduce partials, 16x 3x3 invert, emit E-step coeffs ----------
// partials: [slot = t*10+k][nb].  params per cluster t, stride 12:
// [0..2]=P*mu, [3]=c0, [4..6]=-0.5*Pii, [7..9]=-Pij (01,02,12), [10..11]=pad
__global__ __launch_bounds__(1024) void k_params(const float* __restrict__ partials,
                                                 float* __restrict__ params,
                                                 int nb) {
    __shared__ float qs[4][160];
    __shared__ float sums[160];
    __shared__ float wtab[16];
    const int t = threadIdx.x & 255;
    const int q = threadIdx.x >> 8;
    if (t < 160) {
        const int per = nb >> 2;
        const float4* pp = (const float4*)(partials + (size_t)t * nb + q * per);
        float s = 0.f;
        #pragma unroll 8
        for (int i = 0; i < (per >> 2); ++i) {
            float4 v = pp[i];
            s += (v.x + v.y) + (v.z + v.w);
        }
        qs[q][t] = s;
    }
    __syncthreads();
    if (threadIdx.x < 160)
        sums[threadIdx.x] = qs[0][threadIdx.x] + qs[1][threadIdx.x]
                          + qs[2][threadIdx.x] + qs[3][threadIdx.x];
    __syncthreads();
    if (threadIdx.x < 16) wtab[threadIdx.x] = sums[threadIdx.x * 10] + EPS_F;
    __syncthreads();
    if (threadIdx.x < 16) {
        const int tt = threadIdx.x;
        const float* S = &sums[tt * 10];
        const float w  = wtab[tt];
        const float iw = 1.0f / w;
        float mu0 = S[1] * iw, mu1 = S[2] * iw, mu2 = S[3] * iw;
        float c00 = S[4] * iw - mu0 * mu0 + EPS_F;
        float c01 = S[5] * iw - mu0 * mu1;
        float c02 = S[6] * iw - mu0 * mu2;
        float c11 = S[7] * iw - mu1 * mu1 + EPS_F;
        float c12 = S[8] * iw - mu1 * mu2;
        float c22 = S[9] * iw - mu2 * mu2 + EPS_F;
        float d00 = c11 * c22 - c12 * c12;
        float d01 = c02 * c12 - c01 * c22;
        float d02 = c01 * c12 - c02 * c11;
        float det = c00 * d00 + c01 * d01 + c02 * d02;
        float idet = 1.0f / det;
        float P00 = d00 * idet, P01 = d01 * idet, P02 = d02 * idet;
        float P11 = (c00 * c22 - c02 * c02) * idet;
        float P12 = (c01 * c02 - c00 * c12) * idet;
        float P22 = (c00 * c11 - c01 * c01) * idet;
        float logdet = logf(det);
        const int mb = tt & 12;
        float wsum = wtab[mb] + wtab[mb + 1] + wtab[mb + 2] + wtab[mb + 3];
        float logpi = logf(w) - logf(wsum);
        float pm0 = P00 * mu0 + P01 * mu1 + P02 * mu2;
        float pm1 = P01 * mu0 + P11 * mu1 + P12 * mu2;
        float pm2 = P02 * mu0 + P12 * mu1 + P22 * mu2;
        float mPm = mu0 * pm0 + mu1 * pm1 + mu2 * pm2;
        float c0 = logpi - 0.5f * (mPm + logdet + LOG2PI3);
        float* P = params + tt * 12;
        P[0] = pm0; P[1] = pm1; P[2] = pm2; P[3] = c0;
        P[4] = -0.5f * P00; P[5] = -0.5f * P11; P[6] = -0.5f * P22;
        P[7] = -P01; P[8] = -P02; P[9] = -P12;
        P[10] = 0.f; P[11] = 0.f;
    }
}

// ---------- final: logp for all 16 gaussians -> logsumexp_g -> softmax_m ----------
static __device__ __forceinline__ void final_pixel(const float* __restrict__ PR,
                                                   float a, float b, float c,
                                                   float* post) {
    float xx00 = a * a, xx01 = a * b, xx02 = a * c;
    float xx11 = b * b, xx12 = b * c, xx22 = c * c;
    float ml[4];
    #pragma unroll
    for (int m = 0; m < 4; ++m) {
        float l[4];
        #pragma unroll
        for (int g = 0; g < 4; ++g) {
            const float* P = PR + (m * 4 + g) * 10;
            l[g] = P[3] + P[0] * a + P[1] * b + P[2] * c
                 + P[4] * xx00 + P[5] * xx11 + P[6] * xx22
                 + P[7] * xx01 + P[8] * xx02 + P[9] * xx12;
        }
        float mx = fmaxf(fmaxf(l[0], l[1]), fmaxf(l[2], l[3]));
        ml[m] = mx + __logf(__expf(l[0] - mx) + __expf(l[1] - mx)
                          + __expf(l[2] - mx) + __expf(l[3] - mx));
    }
    float mmx = fmaxf(fmaxf(ml[0], ml[1]), fmaxf(ml[2], ml[3]));
    float e0 = __expf(ml[0] - mmx), e1 = __expf(ml[1] - mmx);
    float e2 = __expf(ml[2] - mmx), e3 = __expf(ml[3] - mmx);
    float rs = 1.0f / (e0 + e1 + e2 + e3);
    post[0] = e0 * rs; post[1] = e1 * rs; post[2] = e2 * rs; post[3] = e3 * rs;
}

__global__ __launch_bounds__(NTHR) void k_final(const float* __restrict__ x,
                                                const float* __restrict__ params,
                                                float* __restrict__ out,
                                                int N) {
    __shared__ __align__(16) float spar[192];
    if (threadIdx.x < 192) spar[threadIdx.x] = params[threadIdx.x];
    __syncthreads();
    float PR[160];
    #pragma unroll
    for (int t = 0; t < 16; ++t) {
        #pragma unroll
        for (int k = 0; k < 10; ++k) PR[t * 10 + k] = spar[t * 12 + k];
    }
    const int groups = N >> 2;
    const float4* x0p = (const float4*)x;
    const float4* x1p = (const float4*)(x + N);
    const float4* x2p = (const float4*)(x + 2 * N);
    const int stride = gridDim.x * NTHR;
    for (int i = blockIdx.x * NTHR + threadIdx.x; i < groups; i += stride) {
        float4 a = x0p[i], b = x1p[i], c = x2p[i];
        float p0[4], p1[4], p2[4], p3[4];
        final_pixel(PR, a.x, b.x, c.x, p0);
        final_pixel(PR, a.y, b.y, c.y, p1);
        final_pixel(PR, a.z, b.z, c.z, p2);
        final_pixel(PR, a.w, b.w, c.w, p3);
        #pragma unroll
        for (int m = 0; m < 4; ++m) {
            ((float4*)(out + (size_t)m * N))[i] =
                make_float4(p0[m], p1[m], p2[m], p3[m]);
        }
    }
}

extern "C" void kernel_launch(void* const* d_in, const int* in_sizes, int n_in,
                              void* d_out, int out_size, void* d_ws, size_t ws_size,
                              hipStream_t stream) {
    const float* x   = (const float*)d_in[0];   // [3, N] float32
    const int*   lab = (const int*)d_in[1];     // [N] int32 in [0,4)
    float* out = (float*)d_out;                 // [4, N] float32
    const int N = in_sizes[1];

    int nb = NBLK;
    while (nb > 128 && ws_size < (size_t)(160 * nb + 192) * sizeof(float)) nb >>= 1;
    float* partials = (float*)d_ws;                    // [160][nb]
    float* params   = partials + (size_t)160 * nb;     // [16*12]

    dim3 grid(nb), blk(NTHR);
    k_accum<<<grid, blk, 0, stream>>>(x, lab, params, partials, N, 0);
    k_params<<<dim3(1), dim3(1024), 0, stream>>>(partials, params, nb);
    k_accum<<<grid, blk, 0, stream>>>(x, lab, params, partials, N, 1);
    k_params<<<dim3(1), dim3(1024), 0, stream>>>(partials, params, nb);
    k_accum<<<grid, blk, 0, stream>>>(x, lab, params, partials, N, 1);
    k_params<<<dim3(1), dim3(1024), 0, stream>>>(partials, params, nb);
    k_final<<<grid, blk, 0, stream>>>(x, params, out, N);
}